// Round 2
// baseline (219.895 us; speedup 1.0000x reference)
//
#include <hip/hip_runtime.h>
#include <cstdint>

// GRU RNN fused persistent kernel for MI355X (gfx950).  T=256,B=4096,D=128,H=16.
// Round 2: barrier-free register scan + register-resident gx + 2-deep DMA pipeline.
//
//  - grid 256 (1 block/CU), 256 threads (4 waves). Block owns 16 batch elems.
//  - h state: 1 float/thread (elem = tid>>4 spans 16 lanes of ONE wave).
//    Scan step = 16 ds_bpermute broadcasts + 48 reg FMAs + gates. NO barriers.
//  - A staged ELEM-MAJOR (row = e*4 + t) so the 16x16x32 MFMA D-fragment
//    (row=lq*4+j, col=li) puts gx for (elem wv*4+lq, t=j, unit li) in the very
//    lane that runs that elem's scan -> gx never touches LDS.
//  - feat chunks (TC=4 steps, 32 KB) double-buffered in LDS via
//    global_load_lds width 16; DMA(c+2) issued after MFMA(c), landing checked
//    with counted vmcnt (9 loads + 1 mask load + 4 out-stores per wave/chunk;
//    waits: c=0 ->9, c=1 ->13, steady ->17, last ->8). Never vmcnt(0) in loop.
//  - 16B-granule XOR swizzle, both-sides (pre-swizzled global source, linear
//    LDS dest; same XOR on ds_read_b128) -> bank-balanced reads.
//  - W_ih in bf16 hi/lo planes; 3-pass split MFMA (hh+lh+hl) for ~f32-exact gx.
//    B-fragments hoisted to registers once (constant over chunks).

#define TT 256
#define BB 4096
#define DD 128
#define HH 16
#define TC 4
#define NCH (TT / TC)  // 64
#define EPB 16

typedef float    f32x4  __attribute__((ext_vector_type(4)));
typedef short    bf16x8 __attribute__((ext_vector_type(8)));
typedef uint32_t u32x4  __attribute__((ext_vector_type(4)));

__global__ __launch_bounds__(256, 1) void gru_fused(
    const float* __restrict__ feat, const float* __restrict__ bmask,
    const float* __restrict__ hx0, const float* __restrict__ Wih,
    const float* __restrict__ Whh, const float* __restrict__ bih,
    const float* __restrict__ bhh, float* __restrict__ out) {
  __shared__ __align__(16) float As[2][TC * EPB * DD];    // 2 x 32 KB
  __shared__ __align__(16) unsigned short Whi[48 * 136];  // 12.75 KB
  __shared__ __align__(16) unsigned short Wlo[48 * 136];  // 12.75 KB
  __shared__ __align__(16) float ms[3][256];              // 3 KB (mask, 3-deep)

  const int tid  = threadIdx.x;
  const int lane = tid & 63;
  const int wv   = tid >> 6;   // wave 0..3
  const int li   = lane & 15;  // MFMA row/col index == hidden unit si
  const int lq   = lane >> 4;  // MFMA quarter == elem-within-wave
  const int b0   = blockIdx.x * EPB;
  const int si   = li;
  const int se   = wv * 4 + lq;  // elem 0..15 (== tid>>4)

  // ---- DMA stage of chunk c: A-tile (elem-major rows, swizzled) + masks ----
  auto stage = [&](int c) {
    char* AsB = (char*)As[c & 1];
    char* msB = (char*)ms[c % 3] + wv * 256;
    const char* base =
        (const char*)(feat + (size_t)c * TC * BB * DD + (size_t)b0 * DD);
#pragma unroll
    for (int k = 0; k < 8; ++k) {
      int s = wv * 8 + k;             // 1KB segment id (wave-uniform)
      int row = 2 * s + (lane >> 5);  // staged row 0..63 = e*4 + tq
      int e = row >> 2, tq = row & 3;
      int inrow = (lane & 31) << 4;   // byte pos within 512B row
      int off = e * (DD * 4) + (inrow ^ ((row & 7) << 4));  // pre-swizzled src
      const char* g = base + (size_t)tq * ((size_t)BB * DD * 4) + off;
      __builtin_amdgcn_global_load_lds(
          (const __attribute__((address_space(1))) void*)g,
          (__attribute__((address_space(3))) void*)(AsB + s * 1024), 16, 0, 0);
    }
    {  // masks: lane l -> tq=l&3, el=(l>>2)&3 (lanes>=16 write harmless dups)
      int tq = lane & 3, el = (lane >> 2) & 3;
      const char* g =
          (const char*)(bmask + (size_t)(c * TC + tq) * BB + b0 + wv * 4 + el);
      __builtin_amdgcn_global_load_lds(
          (const __attribute__((address_space(1))) void*)g,
          (__attribute__((address_space(3))) void*)msB, 4, 0, 0);
    }
  };

  stage(0);
  stage(1);

  // ---- prologue: W_ih -> bf16 hi/lo planes in LDS ----
  for (int idx = tid; idx < 48 * DD; idx += 256) {
    int g = idx >> 7, k = idx & 127;
    float w = Wih[idx];
    uint32_t u = __float_as_uint(w);
    uint32_t h = u & 0xFFFF0000u;       // trunc-to-bf16 (hi)
    float l = w - __uint_as_float(h);   // exact residual
    Whi[g * 136 + k] = (unsigned short)(h >> 16);
    Wlo[g * 136 + k] = (unsigned short)(__float_as_uint(l) >> 16);
  }

  // per-thread W_hh rows (gates r,z,n for unit si) + biases + h init
  float whhA[16], whhB[16], whhC[16];
#pragma unroll
  for (int j = 0; j < 16; ++j) {
    whhA[j] = Whh[si * HH + j];
    whhB[j] = Whh[(si + 16) * HH + j];
    whhC[j] = Whh[(si + 32) * HH + j];
  }
  const float bhA = bhh[si], bhB = bhh[si + 16], bhC = bhh[si + 32];
  const float biA = bih[si], biB = bih[si + 16], biC = bih[si + 32];
  float h = hx0[(size_t)(b0 + se) * HH + si];

  // planes visible to all waves (do NOT drain vmcnt: DMA(0/1) stays in flight)
  asm volatile("s_waitcnt lgkmcnt(0)" ::: "memory");
  __builtin_amdgcn_s_barrier();

  // hoist B fragments (constant across chunks): Bh/Bl[ks][gate]
  bf16x8 Bh[4][3], Bl[4][3];
#pragma unroll
  for (int ks = 0; ks < 4; ++ks)
#pragma unroll
    for (int n = 0; n < 3; ++n) {
      int g = 16 * n + li;
      int wb = g * 272 + ks * 64 + lq * 16;
      Bh[ks][n] = *(const bf16x8*)((const char*)Whi + wb);
      Bl[ks][n] = *(const bf16x8*)((const char*)Wlo + wb);
    }

  for (int c = 0; c < NCH; ++c) {
    // wait for DMA(c) only; keep younger groups in flight.
    // per-wave vmem groups/chunk: 9 loads (8 A + 1 mask) + 4 out-stores.
    if (c == 0)            asm volatile("s_waitcnt vmcnt(9)" ::: "memory");
    else if (c == 1)       asm volatile("s_waitcnt vmcnt(13)" ::: "memory");
    else if (c == NCH - 1) asm volatile("s_waitcnt vmcnt(8)" ::: "memory");
    else                   asm volatile("s_waitcnt vmcnt(17)" ::: "memory");
    __builtin_amdgcn_s_barrier();

    // ========== MFMA: gx for this wave's 4 elems x 4 steps, into regs =======
    const char* AsB = (const char*)As[c & 1];
    f32x4 acc0 = {0.f, 0.f, 0.f, 0.f};
    f32x4 acc1 = {0.f, 0.f, 0.f, 0.f};
    f32x4 acc2 = {0.f, 0.f, 0.f, 0.f};
#pragma unroll
    for (int ks = 0; ks < 4; ++ks) {
      int row = wv * 16 + li;
      int a0o = row * 512 + ((ks * 128 + lq * 32) ^ ((row & 7) << 4));
      f32x4 x0 = *(const f32x4*)(AsB + a0o);
      f32x4 x1 = *(const f32x4*)(AsB + (a0o ^ 16));
      float xs[8] = {x0.x, x0.y, x0.z, x0.w, x1.x, x1.y, x1.z, x1.w};
      uint32_t hiw[4], low[4];
#pragma unroll
      for (int j2 = 0; j2 < 4; ++j2) {
        uint32_t e0 = __float_as_uint(xs[2 * j2]);
        uint32_t e1 = __float_as_uint(xs[2 * j2 + 1]);
        uint32_t h0 = e0 & 0xFFFF0000u, h1 = e1 & 0xFFFF0000u;
        hiw[j2] = (h0 >> 16) | h1;
        float l0 = xs[2 * j2] - __uint_as_float(h0);
        float l1 = xs[2 * j2 + 1] - __uint_as_float(h1);
        low[j2] = (__float_as_uint(l0) >> 16) |
                  (__float_as_uint(l1) & 0xFFFF0000u);
      }
      bf16x8 Ah = __builtin_bit_cast(bf16x8, (u32x4){hiw[0], hiw[1], hiw[2], hiw[3]});
      bf16x8 Al = __builtin_bit_cast(bf16x8, (u32x4){low[0], low[1], low[2], low[3]});
      acc0 = __builtin_amdgcn_mfma_f32_16x16x32_bf16(Ah, Bh[ks][0], acc0, 0, 0, 0);
      acc0 = __builtin_amdgcn_mfma_f32_16x16x32_bf16(Al, Bh[ks][0], acc0, 0, 0, 0);
      acc0 = __builtin_amdgcn_mfma_f32_16x16x32_bf16(Ah, Bl[ks][0], acc0, 0, 0, 0);
      acc1 = __builtin_amdgcn_mfma_f32_16x16x32_bf16(Ah, Bh[ks][1], acc1, 0, 0, 0);
      acc1 = __builtin_amdgcn_mfma_f32_16x16x32_bf16(Al, Bh[ks][1], acc1, 0, 0, 0);
      acc1 = __builtin_amdgcn_mfma_f32_16x16x32_bf16(Ah, Bl[ks][1], acc1, 0, 0, 0);
      acc2 = __builtin_amdgcn_mfma_f32_16x16x32_bf16(Ah, Bh[ks][2], acc2, 0, 0, 0);
      acc2 = __builtin_amdgcn_mfma_f32_16x16x32_bf16(Al, Bh[ks][2], acc2, 0, 0, 0);
      acc2 = __builtin_amdgcn_mfma_f32_16x16x32_bf16(Ah, Bl[ks][2], acc2, 0, 0, 0);
    }
    __builtin_amdgcn_s_barrier();  // all waves done reading As[c&1] -> reusable

    if (c + 2 < NCH) stage(c + 2);  // lands during scan(c) + MFMA(c+1)

    // masks for this chunk (broadcast read, 16B per elem-group)
    f32x4 mm = *(const f32x4*)((const char*)ms[c % 3] + wv * 256 + lq * 16);

    // ========== scan: 4 steps, pure registers + intra-wave bpermute =========
    const int pbase = (lane & 48) << 2;  // 16-lane group base (byte addr)
#pragma unroll
    for (int tq = 0; tq < 4; ++tq) {
      float f = 1.0f - mm[tq];
      float d0 = 0.f, d1 = 0.f, d2 = 0.f;
#pragma unroll
      for (int j = 0; j < 16; ++j) {
        float hj = __uint_as_float((uint32_t)__builtin_amdgcn_ds_bpermute(
            pbase + 4 * j, (int)__float_as_uint(h)));
        d0 = __builtin_fmaf(whhA[j], hj, d0);
        d1 = __builtin_fmaf(whhB[j], hj, d1);
        d2 = __builtin_fmaf(whhC[j], hj, d2);
      }
      float g0 = acc0[tq] + biA;
      float g1 = acc1[tq] + biB;
      float g2 = acc2[tq] + biC;
      float r = 1.0f / (1.0f + __expf(-(g0 + f * d0 + bhA)));
      float z = 1.0f / (1.0f + __expf(-(g1 + f * d1 + bhB)));
      float a = g2 + r * (f * d2 + bhC);
      float n = 2.0f / (1.0f + __expf(-2.0f * a)) - 1.0f;  // tanh(a)
      float hm = f * h;
      h = n + z * (hm - n);  // (1-z)*n + z*h'
      out[((size_t)(c * TC + tq) * BB + b0 + se) * HH + si] = h;
    }
  }
}

extern "C" void kernel_launch(void* const* d_in, const int* in_sizes, int n_in,
                              void* d_out, int out_size, void* d_ws,
                              size_t ws_size, hipStream_t stream) {
  const float* feat  = (const float*)d_in[0];
  const float* bmask = (const float*)d_in[1];
  const float* hx0   = (const float*)d_in[2];
  const float* Wih   = (const float*)d_in[3];
  const float* Whh   = (const float*)d_in[4];
  const float* bih   = (const float*)d_in[5];
  const float* bhh   = (const float*)d_in[6];
  float* out = (float*)d_out;
  gru_fused<<<dim3(BB / EPB), dim3(256), 0, stream>>>(feat, bmask, hx0, Wih,
                                                      Whh, bih, bhh, out);
}

// Round 3
// 192.751 us; speedup vs baseline: 1.1408x; 1.1408x over previous
//
#include <hip/hip_runtime.h>
#include <cstdint>

// GRU RNN fused persistent kernel for MI355X (gfx950).  T=256,B=4096,D=128,H=16.
// Round 3: fully barrier-free independent waves + depth-4 continuous DMA pipeline.
//
//  - grid 256 (1 block/CU), 256 threads = 4 waves. Each wave is an INDEPENDENT
//    pipeline owning 4 batch elems: it stages its own A rows, computes its own
//    gx via MFMA (D-fragment lands in exactly the lanes that scan it), and runs
//    a register-only scan (h = 1 float/thread, ds_bpermute broadcasts).
//    Zero s_barrier in the whole kernel.
//  - W_ih fragments loaded global->registers (bf16 hi/lo split, 3-pass MFMA
//    hh+lh+hl for ~f32-exact gx). No LDS for weights.
//  - LDS = 4-deep circular feat buffer (4 x 32KB) + masks. Per wave, chunks
//    c+1..c+3 stay in flight => ~96KB/CU outstanding continuously (vs ~15-30KB
//    in R2's bursty scheme, which capped HBM at ~2.5 TB/s).
//  - Counted per-wave vmcnt (9 loads + 4 stores per wave per chunk):
//    wait(c) = 27/31/35/39 for c=0..3, 43 steady, 34/25/16 tail. Never vmcnt(0).
//  - 16B-granule XOR swizzle, both-sides (pre-swizzled global source, linear
//    LDS dest, same XOR on ds_read_b128) -> bank-balanced MFMA A reads.

#define TT 256
#define BB 4096
#define DD 128
#define HH 16
#define TC 4
#define NCH (TT / TC)  // 64
#define EPB 16

typedef float    f32x4  __attribute__((ext_vector_type(4)));
typedef short    bf16x8 __attribute__((ext_vector_type(8)));
typedef uint32_t u32x4  __attribute__((ext_vector_type(4)));

__global__ __launch_bounds__(256, 1) void gru_fused(
    const float* __restrict__ feat, const float* __restrict__ bmask,
    const float* __restrict__ hx0, const float* __restrict__ Wih,
    const float* __restrict__ Whh, const float* __restrict__ bih,
    const float* __restrict__ bhh, float* __restrict__ out) {
  __shared__ __align__(16) float As[4][TC * EPB * DD];  // 4 x 32 KB circular
  __shared__ __align__(16) float ms[4][256];            // 4 KB (mask, 4-deep)

  const int tid  = threadIdx.x;
  const int lane = tid & 63;
  const int wv   = tid >> 6;   // wave 0..3 (independent pipeline)
  const int li   = lane & 15;  // MFMA row/col index == hidden unit si
  const int lq   = lane >> 4;  // MFMA quarter == elem-within-wave
  const int b0   = blockIdx.x * EPB;
  const int si   = li;
  const int se   = wv * 4 + lq;  // elem 0..15 (== tid>>4)

  // ---- DMA stage of chunk c: this wave's A rows (elem-major, swizzled) ----
  auto stage = [&](int c) {
    char* AsB = (char*)As[c & 3];
    char* msB = (char*)ms[c & 3] + wv * 256;
    const char* base =
        (const char*)(feat + (size_t)c * TC * BB * DD + (size_t)b0 * DD);
#pragma unroll
    for (int k = 0; k < 8; ++k) {
      int s = wv * 8 + k;             // 1KB segment id (wave-uniform)
      int row = 2 * s + (lane >> 5);  // staged row 0..63 = e*4 + tq
      int e = row >> 2, tq = row & 3;
      int inrow = (lane & 31) << 4;   // byte pos within 512B row
      int off = e * (DD * 4) + (inrow ^ ((row & 7) << 4));  // pre-swizzled src
      const char* g = base + (size_t)tq * ((size_t)BB * DD * 4) + off;
      __builtin_amdgcn_global_load_lds(
          (const __attribute__((address_space(1))) void*)g,
          (__attribute__((address_space(3))) void*)(AsB + s * 1024), 16, 0, 0);
    }
    {  // masks: lane l -> tq=l&3, el=(l>>2)&3 (lanes>=16 write harmless dups)
      int tq = lane & 3, el = (lane >> 2) & 3;
      const char* g =
          (const char*)(bmask + (size_t)(c * TC + tq) * BB + b0 + wv * 4 + el);
      __builtin_amdgcn_global_load_lds(
          (const __attribute__((address_space(1))) void*)g,
          (__attribute__((address_space(3))) void*)msB, 4, 0, 0);
    }
  };

  // ---- W_ih fragments: global -> registers, bf16 hi/lo split ----
  // (done BEFORE staging so the compiler's waits for these drain only W loads)
  bf16x8 Bh[4][3], Bl[4][3];
#pragma unroll
  for (int ks = 0; ks < 4; ++ks)
#pragma unroll
    for (int n = 0; n < 3; ++n) {
      const char* wp =
          (const char*)Wih + (16 * n + li) * 512 + ks * 128 + lq * 32;
      f32x4 w0 = *(const f32x4*)wp;
      f32x4 w1 = *(const f32x4*)(wp + 16);
      float wsv[8] = {w0.x, w0.y, w0.z, w0.w, w1.x, w1.y, w1.z, w1.w};
      uint32_t hiw[4], low[4];
#pragma unroll
      for (int j2 = 0; j2 < 4; ++j2) {
        uint32_t e0 = __float_as_uint(wsv[2 * j2]);
        uint32_t e1 = __float_as_uint(wsv[2 * j2 + 1]);
        uint32_t h0 = e0 & 0xFFFF0000u, h1 = e1 & 0xFFFF0000u;
        hiw[j2] = (h0 >> 16) | h1;
        float l0 = wsv[2 * j2] - __uint_as_float(h0);
        float l1 = wsv[2 * j2 + 1] - __uint_as_float(h1);
        low[j2] = (__float_as_uint(l0) >> 16) |
                  (__float_as_uint(l1) & 0xFFFF0000u);
      }
      Bh[ks][n] = __builtin_bit_cast(bf16x8, (u32x4){hiw[0], hiw[1], hiw[2], hiw[3]});
      Bl[ks][n] = __builtin_bit_cast(bf16x8, (u32x4){low[0], low[1], low[2], low[3]});
    }

  // per-thread W_hh rows (gates r,z,n for unit si) + biases + h init
  float whhA[16], whhB[16], whhC[16];
#pragma unroll
  for (int j = 0; j < 16; ++j) {
    whhA[j] = Whh[si * HH + j];
    whhB[j] = Whh[(si + 16) * HH + j];
    whhC[j] = Whh[(si + 32) * HH + j];
  }
  const float bhA = bhh[si], bhB = bhh[si + 16], bhC = bhh[si + 32];
  const float biA = bih[si], biB = bih[si + 16], biC = bih[si + 32];
  float h = hx0[(size_t)(b0 + se) * HH + si];

  // ---- prologue pipeline fill: 4 chunks in flight ----
  stage(0);
  stage(1);
  stage(2);
  stage(3);

  const int pbase = (lane & 48) << 2;  // 16-lane group base (byte addr)

  for (int c = 0; c < NCH; ++c) {
    // wait for stage(c) only (per-wave counted; 9 loads + 4 stores per chunk):
    if (c == 0)            asm volatile("s_waitcnt vmcnt(27)" ::: "memory");
    else if (c == 1)       asm volatile("s_waitcnt vmcnt(31)" ::: "memory");
    else if (c == 2)       asm volatile("s_waitcnt vmcnt(35)" ::: "memory");
    else if (c == 3)       asm volatile("s_waitcnt vmcnt(39)" ::: "memory");
    else if (c == NCH - 3) asm volatile("s_waitcnt vmcnt(34)" ::: "memory");
    else if (c == NCH - 2) asm volatile("s_waitcnt vmcnt(25)" ::: "memory");
    else if (c == NCH - 1) asm volatile("s_waitcnt vmcnt(16)" ::: "memory");
    else                   asm volatile("s_waitcnt vmcnt(43)" ::: "memory");

    // masks for this chunk (read BEFORE re-staging this buffer slot)
    f32x4 mm = *(const f32x4*)((const char*)ms[c & 3] + wv * 256 + lq * 16);

    // ========== MFMA: gx for this wave's 4 elems x 4 steps, into regs =======
    const char* AsB = (const char*)As[c & 3];
    f32x4 acc0 = {0.f, 0.f, 0.f, 0.f};
    f32x4 acc1 = {0.f, 0.f, 0.f, 0.f};
    f32x4 acc2 = {0.f, 0.f, 0.f, 0.f};
#pragma unroll
    for (int ks = 0; ks < 4; ++ks) {
      int row = wv * 16 + li;
      int a0o = row * 512 + ((ks * 128 + lq * 32) ^ ((row & 7) << 4));
      f32x4 x0 = *(const f32x4*)(AsB + a0o);
      f32x4 x1 = *(const f32x4*)(AsB + (a0o ^ 16));
      float xs[8] = {x0.x, x0.y, x0.z, x0.w, x1.x, x1.y, x1.z, x1.w};
      uint32_t hiw[4], low[4];
#pragma unroll
      for (int j2 = 0; j2 < 4; ++j2) {
        uint32_t e0 = __float_as_uint(xs[2 * j2]);
        uint32_t e1 = __float_as_uint(xs[2 * j2 + 1]);
        uint32_t h0 = e0 & 0xFFFF0000u, h1 = e1 & 0xFFFF0000u;
        hiw[j2] = (h0 >> 16) | h1;
        float l0 = xs[2 * j2] - __uint_as_float(h0);
        float l1 = xs[2 * j2 + 1] - __uint_as_float(h1);
        low[j2] = (__float_as_uint(l0) >> 16) |
                  (__float_as_uint(l1) & 0xFFFF0000u);
      }
      bf16x8 Ah = __builtin_bit_cast(bf16x8, (u32x4){hiw[0], hiw[1], hiw[2], hiw[3]});
      bf16x8 Al = __builtin_bit_cast(bf16x8, (u32x4){low[0], low[1], low[2], low[3]});
      acc0 = __builtin_amdgcn_mfma_f32_16x16x32_bf16(Ah, Bh[ks][0], acc0, 0, 0, 0);
      acc0 = __builtin_amdgcn_mfma_f32_16x16x32_bf16(Al, Bh[ks][0], acc0, 0, 0, 0);
      acc0 = __builtin_amdgcn_mfma_f32_16x16x32_bf16(Ah, Bl[ks][0], acc0, 0, 0, 0);
      acc1 = __builtin_amdgcn_mfma_f32_16x16x32_bf16(Ah, Bh[ks][1], acc1, 0, 0, 0);
      acc1 = __builtin_amdgcn_mfma_f32_16x16x32_bf16(Al, Bh[ks][1], acc1, 0, 0, 0);
      acc1 = __builtin_amdgcn_mfma_f32_16x16x32_bf16(Ah, Bl[ks][1], acc1, 0, 0, 0);
      acc2 = __builtin_amdgcn_mfma_f32_16x16x32_bf16(Ah, Bh[ks][2], acc2, 0, 0, 0);
      acc2 = __builtin_amdgcn_mfma_f32_16x16x32_bf16(Al, Bh[ks][2], acc2, 0, 0, 0);
      acc2 = __builtin_amdgcn_mfma_f32_16x16x32_bf16(Ah, Bl[ks][2], acc2, 0, 0, 0);
    }

    // refill the slot we just consumed (alias on As/ms prevents hoisting
    // these LDS-writes above the reads; no barrier needed: wave-private rows)
    if (c + 4 < NCH) stage(c + 4);

    // ========== scan: 4 steps, pure registers + intra-wave bpermute =========
#pragma unroll
    for (int tq = 0; tq < 4; ++tq) {
      float f = 1.0f - mm[tq];
      float d0 = 0.f, d1 = 0.f, d2 = 0.f;
#pragma unroll
      for (int j = 0; j < 16; ++j) {
        float hj = __uint_as_float((uint32_t)__builtin_amdgcn_ds_bpermute(
            pbase + 4 * j, (int)__float_as_uint(h)));
        d0 = __builtin_fmaf(whhA[j], hj, d0);
        d1 = __builtin_fmaf(whhB[j], hj, d1);
        d2 = __builtin_fmaf(whhC[j], hj, d2);
      }
      float g0 = acc0[tq] + biA;
      float g1 = acc1[tq] + biB;
      float g2 = acc2[tq] + biC;
      float r = 1.0f / (1.0f + __expf(-(g0 + f * d0 + bhA)));
      float z = 1.0f / (1.0f + __expf(-(g1 + f * d1 + bhB)));
      float a = g2 + r * (f * d2 + bhC);
      float n = 2.0f / (1.0f + __expf(-2.0f * a)) - 1.0f;  // tanh(a)
      float hm = f * h;
      h = n + z * (hm - n);  // (1-z)*n + z*h'
      out[((size_t)(c * TC + tq) * BB + b0 + se) * HH + si] = h;
    }
  }
}

extern "C" void kernel_launch(void* const* d_in, const int* in_sizes, int n_in,
                              void* d_out, int out_size, void* d_ws,
                              size_t ws_size, hipStream_t stream) {
  const float* feat  = (const float*)d_in[0];
  const float* bmask = (const float*)d_in[1];
  const float* hx0   = (const float*)d_in[2];
  const float* Wih   = (const float*)d_in[3];
  const float* Whh   = (const float*)d_in[4];
  const float* bih   = (const float*)d_in[5];
  const float* bhh   = (const float*)d_in[6];
  float* out = (float*)d_out;
  gru_fused<<<dim3(BB / EPB), dim3(256), 0, stream>>>(feat, bmask, hx0, Wih,
                                                      Whh, bih, bhh, out);
}